// Round 13
// baseline (514.173 us; speedup 1.0000x reference)
//
#include <hip/hip_runtime.h>
#include <math.h>

// ---- problem constants (fixed by the reference) ----
constexpr int N_NODES = 20000;
constexpr int N_EDGES = 320000;
constexpr int N_GRAPH = 200;
constexpr int F_IN    = 128;
constexpr int NH      = 4;
constexpr int O1 = 64,  O2 = 128, O3 = 256;
constexpr int D1 = 256, D2 = 512, D3 = 1024;
constexpr int LAT  = 128;
constexpr int HIDG = 128;
constexpr int KS_HEADS = 8;
constexpr float NEG_SLOPE = 0.2f;

typedef __attribute__((ext_vector_type(8))) short bf16x8;
typedef __attribute__((ext_vector_type(4))) float f32x4;
typedef __attribute__((ext_vector_type(2))) ushort ushortx2;

// bf16 split: x ~= hi + lo, both RNE-rounded bf16 (stored as raw ushort)
__device__ inline void bsplit(float x, ushort& h, ushort& l) {
    unsigned u = __float_as_uint(x);
    unsigned rh = (u + 0x7fffu + ((u >> 16) & 1u)) & 0xffff0000u;
    h = (ushort)(rh >> 16);
    float res = x - __uint_as_float(rh);
    unsigned u2 = __float_as_uint(res);
    l = (ushort)((u2 + 0x7fffu + ((u2 >> 16) & 1u)) >> 16);
}
__device__ inline ushort f2bf(float x) {
    unsigned u = __float_as_uint(x);
    return (ushort)((u + 0x7fffu + ((u >> 16) & 1u)) >> 16);
}
__device__ inline float bf2f(ushort u) { return __uint_as_float(((unsigned)u) << 16); }

// ================= CSR build =================
__global__ void zero_int(int* __restrict__ p, int n) {
    int i = blockIdx.x * blockDim.x + threadIdx.x;
    if (i < n) p[i] = 0;
}

__global__ void count_deg(const int* __restrict__ dst, int* __restrict__ deg) {
    int e = blockIdx.x * blockDim.x + threadIdx.x;
    if (e < N_EDGES) atomicAdd(&deg[dst[e]], 1);
}

constexpr int SCAN_B = 512;
__global__ __launch_bounds__(SCAN_B)
void scan1(const int* __restrict__ deg, int* __restrict__ rowptr, int* __restrict__ bsum) {
    __shared__ int s[SCAN_B];
    int tid = threadIdx.x;
    int i = blockIdx.x * SCAN_B + tid;
    int v = (i < N_NODES) ? deg[i] : 0;
    s[tid] = v;
    __syncthreads();
    for (int off = 1; off < SCAN_B; off <<= 1) {
        int add = (tid >= off) ? s[tid - off] : 0;
        __syncthreads();
        s[tid] += add;
        __syncthreads();
    }
    if (i < N_NODES) rowptr[i] = s[tid] - v;
    if (tid == SCAN_B - 1) bsum[blockIdx.x] = s[tid];
}

__global__ void scan2(const int* __restrict__ bsum, int* __restrict__ boff, int nblk) {
    if (threadIdx.x == 0 && blockIdx.x == 0) {
        int run = 0;
        for (int b = 0; b < nblk; ++b) { boff[b] = run; run += bsum[b]; }
    }
}

__global__ __launch_bounds__(SCAN_B)
void scan3(int* __restrict__ rowptr, const int* __restrict__ boff, int* __restrict__ pos) {
    int i = blockIdx.x * SCAN_B + threadIdx.x;
    if (i < N_NODES) {
        int v = rowptr[i] + boff[blockIdx.x];
        rowptr[i] = v;
        pos[i] = v;
    }
    if (i == 0) rowptr[N_NODES] = N_EDGES;
}

__global__ void fill_csr(const int* __restrict__ src, const int* __restrict__ dst,
                         int* __restrict__ pos, int* __restrict__ csr_src) {
    int e = blockIdx.x * blockDim.x + threadIdx.x;
    if (e >= N_EDGES) return;
    int slot = atomicAdd(&pos[dst[e]], 1);
    csr_src[slot] = src[e];
}

__global__ void gptr_kernel(const int* __restrict__ gid, int* __restrict__ gptr) {
    int g = blockIdx.x * blockDim.x + threadIdx.x;
    if (g > N_GRAPH) return;
    int lo = 0, hi = N_NODES;
    while (lo < hi) { int mid = (lo + hi) >> 1; if (gid[mid] < g) lo = mid + 1; else hi = mid; }
    gptr[g] = lo;
}

// ================= conversion kernels =================
__global__ void split_x(const float* __restrict__ X, ushort* __restrict__ S, int M, int K) {
    int i = blockIdx.x * 256 + threadIdx.x;
    int total = (M * K) >> 2;
    if (i >= total) return;
    int e0 = i << 2;
    int m = e0 / K, k = e0 % K;
    float4 v = *(const float4*)&X[(size_t)m * K + k];
    ushort h[4], l[4];
    bsplit(v.x, h[0], l[0]); bsplit(v.y, h[1], l[1]);
    bsplit(v.z, h[2], l[2]); bsplit(v.w, h[3], l[3]);
    uint2 hp, lp;
    hp.x = (unsigned)h[0] | ((unsigned)h[1] << 16);
    hp.y = (unsigned)h[2] | ((unsigned)h[3] << 16);
    lp.x = (unsigned)l[0] | ((unsigned)l[1] << 16);
    lp.y = (unsigned)l[2] | ((unsigned)l[3] << 16);
    *(uint2*)&S[(size_t)m * 2 * K + k] = hp;
    *(uint2*)&S[(size_t)m * 2 * K + K + k] = lp;
}

__global__ __launch_bounds__(256)
void split_wt(const float* __restrict__ W, ushort* __restrict__ Bt, int K, int N) {
    __shared__ float t[32][33];
    int n0 = blockIdx.x * 32, k0 = blockIdx.y * 32;
    int tx = threadIdx.x, ty = threadIdx.y;   // 32 x 8
    for (int j = 0; j < 32; j += 8)
        t[ty + j][tx] = W[(size_t)(k0 + ty + j) * N + n0 + tx];
    __syncthreads();
    for (int j = 0; j < 32; j += 8) {
        float v = t[tx][ty + j];
        int n = n0 + ty + j, k = k0 + tx;
        ushort h, l;
        bsplit(v, h, l);
        Bt[(size_t)n * 2 * K + k] = h;
        Bt[(size_t)n * 2 * K + K + k] = l;
    }
}

// ================= bf16x3 merged-segment MFMA GEMM =================
// OMODE: 0 = f32 out, 1 = bf16 out, 2 = f32 K-split partial.
// OSHIFT > 0: fuse GAT attention halves -- atomicAdd partial el/er dots
// computed from the fp32 accumulator (el/er must be pre-zeroed).
#define GLOAD_LDS16(g, s) \
    __builtin_amdgcn_global_load_lds((const __attribute__((address_space(1))) void*)(g), \
                                     (__attribute__((address_space(3))) void*)(s), 16, 0, 0)

template<bool BIAS, bool RELU, int OMODE, int OSHIFT>
__global__ __launch_bounds__(256)
void gemm_mfma(const ushort* __restrict__ Asp, const ushort* __restrict__ Bt,
               const float* __restrict__ bias, void* __restrict__ Cout,
               int M, int N, int K, int ntn, int kchunk,
               const float* __restrict__ al, const float* __restrict__ ar,
               float* __restrict__ el, float* __restrict__ er) {
    __shared__ __align__(16) ushort lds[4 * 128 * 64];   // 64 KB
    constexpr int AH = 0, AL = 128 * 64, BH = 2 * 128 * 64, BL = 3 * 128 * 64;

    const int nwg = gridDim.x;
    int bid = blockIdx.x;
    int q = nwg >> 3, r = nwg & 7;
    int xcd = bid & 7, local = bid >> 3;
    int wg = (xcd < r) ? (xcd * (q + 1) + local) : (r * (q + 1) + (xcd - r) * q + local);
    const int tm = wg / ntn, tn = wg % ntn;

    const int tid = threadIdx.x;
    const int w = tid >> 6, l = tid & 63;
    const int wr = w >> 1, wc = w & 1;
    const size_t sA = 2 * (size_t)K;

    const int ld8 = l >> 3;
    const int stg_col = ((l & 7) ^ ld8) << 3;
    const int r15 = l & 15, kq = l >> 4;
    const int swz = (l & 7) << 4;

    const int k_begin = blockIdx.y * kchunk;
    const int k_end = (k_begin + kchunk < K) ? (k_begin + kchunk) : K;

    f32x4 acc[4][4];
    #pragma unroll
    for (int m = 0; m < 4; ++m)
        #pragma unroll
        for (int n = 0; n < 4; ++n)
            acc[m][n] = 0.f;

    for (int k0 = k_begin; k0 < k_end; k0 += 64) {
        #pragma unroll
        for (int i = 0; i < 4; ++i) {
            int r0 = w * 32 + i * 8;
            int garow = tm * 128 + r0 + ld8;
            if (garow > M - 1) garow = M - 1;
            const ushort* gaH = Asp + (size_t)garow * sA + k0 + stg_col;
            GLOAD_LDS16(gaH, &lds[AH + r0 * 64]);
            GLOAD_LDS16(gaH + K, &lds[AL + r0 * 64]);
            int gbrow = tn * 128 + r0 + ld8;
            const ushort* gbH = Bt + (size_t)gbrow * sA + k0 + stg_col;
            GLOAD_LDS16(gbH, &lds[BH + r0 * 64]);
            GLOAD_LDS16(gbH + K, &lds[BL + r0 * 64]);
        }
        asm volatile("s_waitcnt vmcnt(0)");
        __syncthreads();

        #pragma unroll
        for (int ks = 0; ks < 2; ++ks) {
            const int kbyte = (ks * 64 + kq * 16) ^ swz;
            bf16x8 ah[4], bh[4], xl[4];
            #pragma unroll
            for (int m = 0; m < 4; ++m) {
                int row = wr * 64 + m * 16 + r15;
                ah[m] = *(const bf16x8*)((const char*)&lds[AH] + row * 128 + kbyte);
            }
            #pragma unroll
            for (int n = 0; n < 4; ++n) {
                int row = wc * 64 + n * 16 + r15;
                bh[n] = *(const bf16x8*)((const char*)&lds[BH] + row * 128 + kbyte);
            }
            #pragma unroll
            for (int m = 0; m < 4; ++m)
                #pragma unroll
                for (int n = 0; n < 4; ++n)
                    acc[m][n] = __builtin_amdgcn_mfma_f32_16x16x32_bf16(ah[m], bh[n], acc[m][n], 0, 0, 0);
            #pragma unroll
            for (int m = 0; m < 4; ++m) {
                int row = wr * 64 + m * 16 + r15;
                xl[m] = *(const bf16x8*)((const char*)&lds[AL] + row * 128 + kbyte);
            }
            #pragma unroll
            for (int m = 0; m < 4; ++m)
                #pragma unroll
                for (int n = 0; n < 4; ++n)
                    acc[m][n] = __builtin_amdgcn_mfma_f32_16x16x32_bf16(xl[m], bh[n], acc[m][n], 0, 0, 0);
            #pragma unroll
            for (int n = 0; n < 4; ++n) {
                int row = wc * 64 + n * 16 + r15;
                xl[n] = *(const bf16x8*)((const char*)&lds[BL] + row * 128 + kbyte);
            }
            #pragma unroll
            for (int m = 0; m < 4; ++m)
                #pragma unroll
                for (int n = 0; n < 4; ++n)
                    acc[m][n] = __builtin_amdgcn_mfma_f32_16x16x32_bf16(ah[m], xl[n], acc[m][n], 0, 0, 0);
        }
        __syncthreads();
    }

    // ---- epilogue: C write ----
    #pragma unroll
    for (int m = 0; m < 4; ++m) {
        #pragma unroll
        for (int n = 0; n < 4; ++n) {
            #pragma unroll
            for (int j = 0; j < 4; ++j) {
                int row = tm * 128 + wr * 64 + m * 16 + kq * 4 + j;
                int col = tn * 128 + wc * 64 + n * 16 + r15;
                if (row < M) {
                    float v = acc[m][n][j];
                    if (BIAS) v += bias[col];
                    if (RELU) v = fmaxf(v, 0.f);
                    if (OMODE == 1)
                        ((ushort*)Cout)[(size_t)row * N + col] = f2bf(v);
                    else if (OMODE == 2)
                        ((float*)Cout)[(size_t)blockIdx.y * M * N + (size_t)row * N + col] = v;
                    else
                        ((float*)Cout)[(size_t)row * N + col] = v;
                }
            }
        }
    }

    // ---- fused attention halves (el/er partial dots) ----
    if (OSHIFT > 0) {
        const int hh = (tn * 128 + wc * 64) >> OSHIFT;   // uniform per (block, wave-col)
        float alv[4], arv[4];
        #pragma unroll
        for (int n = 0; n < 4; ++n) {
            int col = tn * 128 + wc * 64 + n * 16 + r15;
            alv[n] = al[col];
            arv[n] = ar[col];
        }
        #pragma unroll
        for (int m = 0; m < 4; ++m) {
            #pragma unroll
            for (int j = 0; j < 4; ++j) {
                float sl = 0.f, sr = 0.f;
                #pragma unroll
                for (int n = 0; n < 4; ++n) {
                    sl += acc[m][n][j] * alv[n];
                    sr += acc[m][n][j] * arv[n];
                }
                #pragma unroll
                for (int off = 1; off < 16; off <<= 1) {
                    sl += __shfl_xor(sl, off);
                    sr += __shfl_xor(sr, off);
                }
                if (r15 == 0) {
                    int row = tm * 128 + wr * 64 + m * 16 + kq * 4 + j;
                    if (row < M) {
                        atomicAdd(&el[row * NH + hh], sl);
                        atomicAdd(&er[row * NH + hh], sr);
                    }
                }
            }
        }
    }
}

// ================= per-dst edge softmax over CSR (head-major csr_e) =========
__global__ __launch_bounds__(64)
void attn_softmax(const float* __restrict__ el, const float* __restrict__ er,
                  const int* __restrict__ rowptr, const int* __restrict__ csr_src,
                  float* __restrict__ csrE, float* __restrict__ rden) {
    int d = blockIdx.x;
    int lane = threadIdx.x;
    int base = __builtin_amdgcn_readfirstlane(rowptr[d]);
    int end  = __builtin_amdgcn_readfirstlane(rowptr[d + 1]);
    float4 erd = *(const float4*)(er + d * NH);

    float mx[NH] = {-INFINITY, -INFINITY, -INFINITY, -INFINITY};
    for (int s = base + lane; s < end; s += 64) {
        int sn = csr_src[s];
        float4 elv = *(const float4*)(el + sn * NH);
        float e0 = elv.x + erd.x, e1 = elv.y + erd.y;
        float e2 = elv.z + erd.z, e3 = elv.w + erd.w;
        e0 = (e0 >= 0.f) ? e0 : NEG_SLOPE * e0;
        e1 = (e1 >= 0.f) ? e1 : NEG_SLOPE * e1;
        e2 = (e2 >= 0.f) ? e2 : NEG_SLOPE * e2;
        e3 = (e3 >= 0.f) ? e3 : NEG_SLOPE * e3;
        csrE[(size_t)0 * N_EDGES + s] = e0;
        csrE[(size_t)1 * N_EDGES + s] = e1;
        csrE[(size_t)2 * N_EDGES + s] = e2;
        csrE[(size_t)3 * N_EDGES + s] = e3;
        mx[0] = fmaxf(mx[0], e0); mx[1] = fmaxf(mx[1], e1);
        mx[2] = fmaxf(mx[2], e2); mx[3] = fmaxf(mx[3], e3);
    }
    #pragma unroll
    for (int h = 0; h < NH; ++h)
        #pragma unroll
        for (int off = 32; off; off >>= 1)
            mx[h] = fmaxf(mx[h], __shfl_xor(mx[h], off));

    float sm[NH] = {0.f, 0.f, 0.f, 0.f};
    for (int s = base + lane; s < end; s += 64) {
        #pragma unroll
        for (int h = 0; h < NH; ++h) {
            float ex = expf(csrE[(size_t)h * N_EDGES + s] - mx[h]);
            csrE[(size_t)h * N_EDGES + s] = ex;
            sm[h] += ex;
        }
    }
    #pragma unroll
    for (int h = 0; h < NH; ++h)
        #pragma unroll
        for (int off = 32; off; off >>= 1)
            sm[h] += __shfl_xor(sm[h], off);

    if (lane == 0) {
        #pragma unroll
        for (int h = 0; h < NH; ++h)
            rden[d * NH + h] = 1.f / fmaxf(sm[h], 1e-9f);
    }
}

// ================= XCD-pinned gather aggregation (bf16 feat plane) ==========
template<int OSHIFT, int NCH, int D>
__global__ __launch_bounds__(64)
void aggregate_x(const ushort* __restrict__ feat, const float* __restrict__ csrE,
                 const float* __restrict__ rden, const int* __restrict__ rowptr,
                 const int* __restrict__ csr_src, const float* __restrict__ bias,
                 ushort* __restrict__ Ssp) {
    int bid = blockIdx.x;
    int chunk = bid % NCH;
    int d = bid / NCH;
    int t = threadIdx.x;
    int base = __builtin_amdgcn_readfirstlane(rowptr[d]);
    int end  = __builtin_amdgcn_readfirstlane(rowptr[d + 1]);
    const int col0 = chunk * 128 + t * 2;
    const int h = col0 >> OSHIFT;
    const float* eh = csrE + (size_t)h * N_EDGES;
    const ushort* fcol = feat + col0;

    float acc0 = 0.f, acc1 = 0.f;

    int s = base;
    for (; s < end && (s & 3); ++s) {
        int sn = csr_src[s];
        float a = eh[s];
        ushortx2 u = *(const ushortx2*)(fcol + (size_t)sn * D);
        acc0 += bf2f(u[0]) * a; acc1 += bf2f(u[1]) * a;
    }
    for (; s + 7 < end; s += 8) {
        int4 sa = *(const int4*)(csr_src + s);
        int4 sb = *(const int4*)(csr_src + s + 4);
        float4 aa = *(const float4*)(eh + s);
        float4 ab = *(const float4*)(eh + s + 4);
        ushortx2 u0 = *(const ushortx2*)(fcol + (size_t)sa.x * D);
        ushortx2 u1 = *(const ushortx2*)(fcol + (size_t)sa.y * D);
        ushortx2 u2 = *(const ushortx2*)(fcol + (size_t)sa.z * D);
        ushortx2 u3 = *(const ushortx2*)(fcol + (size_t)sa.w * D);
        ushortx2 u4 = *(const ushortx2*)(fcol + (size_t)sb.x * D);
        ushortx2 u5 = *(const ushortx2*)(fcol + (size_t)sb.y * D);
        ushortx2 u6 = *(const ushortx2*)(fcol + (size_t)sb.z * D);
        ushortx2 u7 = *(const ushortx2*)(fcol + (size_t)sb.w * D);
        acc0 += bf2f(u0[0]) * aa.x; acc1 += bf2f(u0[1]) * aa.x;
        acc0 += bf2f(u1[0]) * aa.y; acc1 += bf2f(u1[1]) * aa.y;
        acc0 += bf2f(u2[0]) * aa.z; acc1 += bf2f(u2[1]) * aa.z;
        acc0 += bf2f(u3[0]) * aa.w; acc1 += bf2f(u3[1]) * aa.w;
        acc0 += bf2f(u4[0]) * ab.x; acc1 += bf2f(u4[1]) * ab.x;
        acc0 += bf2f(u5[0]) * ab.y; acc1 += bf2f(u5[1]) * ab.y;
        acc0 += bf2f(u6[0]) * ab.z; acc1 += bf2f(u6[1]) * ab.z;
        acc0 += bf2f(u7[0]) * ab.w; acc1 += bf2f(u7[1]) * ab.w;
    }
    if (s + 3 < end) {
        int4 sn = *(const int4*)(csr_src + s);
        float4 av = *(const float4*)(eh + s);
        ushortx2 u0 = *(const ushortx2*)(fcol + (size_t)sn.x * D);
        ushortx2 u1 = *(const ushortx2*)(fcol + (size_t)sn.y * D);
        ushortx2 u2 = *(const ushortx2*)(fcol + (size_t)sn.z * D);
        ushortx2 u3 = *(const ushortx2*)(fcol + (size_t)sn.w * D);
        acc0 += bf2f(u0[0]) * av.x; acc1 += bf2f(u0[1]) * av.x;
        acc0 += bf2f(u1[0]) * av.y; acc1 += bf2f(u1[1]) * av.y;
        acc0 += bf2f(u2[0]) * av.z; acc1 += bf2f(u2[1]) * av.z;
        acc0 += bf2f(u3[0]) * av.w; acc1 += bf2f(u3[1]) * av.w;
        s += 4;
    }
    for (; s < end; ++s) {
        int sn = csr_src[s];
        float a = eh[s];
        ushortx2 u = *(const ushortx2*)(fcol + (size_t)sn * D);
        acc0 += bf2f(u[0]) * a; acc1 += bf2f(u[1]) * a;
    }

    float rd = rden[d * NH + h];
    float v0 = acc0 * rd + bias[col0];
    float v1 = acc1 * rd + bias[col0 + 1];
    v0 = (v0 > 0.f) ? v0 : expm1f(v0);
    v1 = (v1 > 0.f) ? v1 : expm1f(v1);
    ushort h0, l0, h1, l1;
    bsplit(v0, h0, l0);
    bsplit(v1, h1, l1);
    ushort* hrow = Ssp + (size_t)d * 2 * D;
    ushortx2 hp, lp;
    hp[0] = h0; hp[1] = h1;
    lp[0] = l0; lp[1] = l1;
    *(ushortx2*)(hrow + col0) = hp;
    *(ushortx2*)(hrow + D + col0) = lp;
}

// ================= gate reduce: partials -> gate scalar =================
__global__ __launch_bounds__(128)
void gate_reduce(const float* __restrict__ part, const float* __restrict__ bg1,
                 const float* __restrict__ Wg2, const float* __restrict__ bg2,
                 float* __restrict__ gate) {
    int n = blockIdx.x;
    int t = threadIdx.x;
    constexpr size_t CH = (size_t)N_NODES * HIDG;
    size_t idx = (size_t)n * HIDG + t;
    float v = part[idx] + part[CH + idx] + part[2 * CH + idx] + part[3 * CH + idx] + bg1[t];
    v = fmaxf(v, 0.f) * Wg2[t];
    __shared__ float red[128];
    red[t] = v;
    __syncthreads();
    for (int s = 64; s; s >>= 1) {
        if (t < s) red[t] += red[t + s];
        __syncthreads();
    }
    if (t == 0) gate[n] = red[0] + bg2[0];
}

__global__ __launch_bounds__(64)
void gate_stats(const float* __restrict__ gate, const int* __restrict__ gptr,
                float* __restrict__ anorm) {
    int g = blockIdx.x;
    int lane = threadIdx.x;
    int s = __builtin_amdgcn_readfirstlane(gptr[g]);
    int e = __builtin_amdgcn_readfirstlane(gptr[g + 1]);
    float m = -INFINITY;
    for (int n = s + lane; n < e; n += 64) m = fmaxf(m, gate[n]);
    #pragma unroll
    for (int off = 32; off; off >>= 1) m = fmaxf(m, __shfl_xor(m, off));
    float sum = 0.f;
    for (int n = s + lane; n < e; n += 64) sum += expf(gate[n] - m);
    #pragma unroll
    for (int off = 32; off; off >>= 1) sum += __shfl_xor(sum, off);
    float inv = 1.f / fmaxf(sum, 1e-9f);
    for (int n = s + lane; n < e; n += 64) anorm[n] = expf(gate[n] - m) * inv;
}

// gemb[g] = sum_n anorm[n]*h3[n]; grid (D3/128, G), 64 threads, 2 cols/thread
__global__ __launch_bounds__(64)
void pool_gather(const ushort* __restrict__ h3sp, const float* __restrict__ anorm,
                 const int* __restrict__ gptr, float* __restrict__ gemb) {
    int g = blockIdx.y;
    int col = blockIdx.x * 128 + threadIdx.x * 2;
    float acc0 = 0.f, acc1 = 0.f;
    int s = __builtin_amdgcn_readfirstlane(gptr[g]);
    int e = __builtin_amdgcn_readfirstlane(gptr[g + 1]);
    int n = s;
    for (; n + 3 < e; n += 4) {
        const ushort* r0 = h3sp + (size_t)(n + 0) * 2 * D3;
        const ushort* r1 = h3sp + (size_t)(n + 1) * 2 * D3;
        const ushort* r2 = h3sp + (size_t)(n + 2) * 2 * D3;
        const ushort* r3 = h3sp + (size_t)(n + 3) * 2 * D3;
        float a0 = anorm[n], a1 = anorm[n + 1], a2 = anorm[n + 2], a3 = anorm[n + 3];
        ushortx2 h0 = *(const ushortx2*)(r0 + col), l0 = *(const ushortx2*)(r0 + D3 + col);
        ushortx2 h1 = *(const ushortx2*)(r1 + col), l1 = *(const ushortx2*)(r1 + D3 + col);
        ushortx2 h2 = *(const ushortx2*)(r2 + col), l2 = *(const ushortx2*)(r2 + D3 + col);
        ushortx2 h3 = *(const ushortx2*)(r3 + col), l3 = *(const ushortx2*)(r3 + D3 + col);
        acc0 += a0 * (bf2f(h0[0]) + bf2f(l0[0])); acc1 += a0 * (bf2f(h0[1]) + bf2f(l0[1]));
        acc0 += a1 * (bf2f(h1[0]) + bf2f(l1[0])); acc1 += a1 * (bf2f(h1[1]) + bf2f(l1[1]));
        acc0 += a2 * (bf2f(h2[0]) + bf2f(l2[0])); acc1 += a2 * (bf2f(h2[1]) + bf2f(l2[1]));
        acc0 += a3 * (bf2f(h3[0]) + bf2f(l3[0])); acc1 += a3 * (bf2f(h3[1]) + bf2f(l3[1]));
    }
    for (; n < e; ++n) {
        const ushort* r0 = h3sp + (size_t)n * 2 * D3;
        float a0 = anorm[n];
        ushortx2 h0 = *(const ushortx2*)(r0 + col), l0 = *(const ushortx2*)(r0 + D3 + col);
        acc0 += a0 * (bf2f(h0[0]) + bf2f(l0[0]));
        acc1 += a0 * (bf2f(h0[1]) + bf2f(l0[1]));
    }
    gemb[(size_t)g * D3 + col] = acc0;
    gemb[(size_t)g * D3 + col + 1] = acc1;
}

// ================= heads: k-split partial + reduce =================
__global__ __launch_bounds__(256)
void heads_partial(const float* __restrict__ gemb, const float* __restrict__ Wmu,
                   const float* __restrict__ Wlv, float* __restrict__ part) {
    int g = blockIdx.x, kc = blockIdx.y;
    int t = threadIdx.x;
    int j = t & 127;
    bool lv = t >= 128;
    __shared__ float e[128];
    if (t < 128) e[t] = gemb[(size_t)g * D3 + kc * 128 + t];
    __syncthreads();
    const float* W = (lv ? Wlv : Wmu) + (size_t)(kc * 128) * LAT + j;
    float s = 0.f;
    #pragma unroll 8
    for (int k = 0; k < 128; ++k) s += e[k] * W[(size_t)k * LAT];
    part[((size_t)kc * N_GRAPH + g) * 256 + t] = s;
}

__global__ __launch_bounds__(256)
void heads_reduce(const float* __restrict__ part, const float* __restrict__ bmu,
                  const float* __restrict__ blv, float* __restrict__ out) {
    int g = blockIdx.x;
    int t = threadIdx.x;
    int j = t & 127;
    bool lv = t >= 128;
    float s = 0.f;
    #pragma unroll
    for (int kc = 0; kc < KS_HEADS; ++kc)
        s += part[((size_t)kc * N_GRAPH + g) * 256 + t];
    s += (lv ? blv : bmu)[j];
    out[(lv ? (size_t)N_GRAPH * LAT : 0) + (size_t)g * LAT + j] = s;
}

// ================= host launch =================
extern "C" void kernel_launch(void* const* d_in, const int* in_sizes, int n_in,
                              void* d_out, int out_size, void* d_ws, size_t ws_size,
                              hipStream_t stream) {
    const float* node_feat = (const float*)d_in[0];
    const int*   src = (const int*)d_in[1];
    const int*   dst = (const int*)d_in[2];
    const int*   gid = (const int*)d_in[3];
    const float* W1  = (const float*)d_in[4];
    const float* al1 = (const float*)d_in[5];
    const float* ar1 = (const float*)d_in[6];
    const float* b1  = (const float*)d_in[7];
    const float* W2  = (const float*)d_in[8];
    const float* al2 = (const float*)d_in[9];
    const float* ar2 = (const float*)d_in[10];
    const float* b2  = (const float*)d_in[11];
    const float* W3  = (const float*)d_in[12];
    const float* al3 = (const float*)d_in[13];
    const float* ar3 = (const float*)d_in[14];
    const float* b3  = (const float*)d_in[15];
    const float* Wg1 = (const float*)d_in[16];
    const float* bg1 = (const float*)d_in[17];
    const float* Wg2 = (const float*)d_in[18];
    const float* bg2 = (const float*)d_in[19];
    const float* Wmu = (const float*)d_in[20];
    const float* bmu = (const float*)d_in[21];
    const float* Wlv = (const float*)d_in[22];
    const float* blv = (const float*)d_in[23];
    float* out = (float*)d_out;

    // ---- workspace carve ----
    char* wsb = (char*)d_ws;
    float* bufA   = (float*)wsb;                                   // N*D3 f32 region
    wsb += (size_t)N_NODES * D3 * 4;
    ushort* Xsp   = (ushort*)wsb;                                  // N*2048 bf16 (split acts)
    wsb += (size_t)N_NODES * 2048 * 2;
    ushort* Bt1   = (ushort*)wsb; wsb += (size_t)D1 * 2 * F_IN * 2;
    ushort* Bt2   = (ushort*)wsb; wsb += (size_t)D2 * 2 * D1 * 2;
    ushort* Bt3   = (ushort*)wsb; wsb += (size_t)D3 * 2 * D2 * 2;
    ushort* Btg   = (ushort*)wsb; wsb += (size_t)HIDG * 2 * D3 * 2;
    float* el     = (float*)wsb;  wsb += (size_t)N_NODES * NH * 4;
    float* er     = (float*)wsb;  wsb += (size_t)N_NODES * NH * 4;
    float* rden   = (float*)wsb;  wsb += (size_t)N_NODES * NH * 4;
    float* csrE   = (float*)wsb;  wsb += (size_t)N_EDGES * NH * 4;  // head-major [NH][E]
    float* gate   = (float*)wsb;  wsb += (size_t)N_NODES * 4;
    float* anorm  = (float*)wsb;  wsb += (size_t)N_NODES * 4;
    int* deg      = (int*)wsb;    wsb += (size_t)N_NODES * 4;
    int* rowptr   = (int*)wsb;    wsb += (size_t)(N_NODES + 1) * 4;
    int* pos      = (int*)wsb;    wsb += (size_t)N_NODES * 4;
    int* csr_src  = (int*)wsb;    wsb += (size_t)N_EDGES * 4;
    int* bsum     = (int*)wsb;    wsb += 64 * 4;
    int* boff     = (int*)wsb;    wsb += 64 * 4;
    int* gptr     = (int*)wsb;    wsb += (size_t)(N_GRAPH + 1) * 4;
    ushort* featb = (ushort*)bufA;                                 // bf16 feat plane alias
    float* partial = bufA;                                         // pool K-split partials (4*N*128)
    float* gemb   = bufA + (size_t)4 * N_NODES * HIDG;             // G*D3
    float* hpart  = gemb + (size_t)N_GRAPH * D3;                   // KS*G*256

    // ---- CSR build ----
    constexpr int NBLK = (N_NODES + SCAN_B - 1) / SCAN_B;
    zero_int<<<dim3((N_NODES + 255) / 256), dim3(256), 0, stream>>>(deg, N_NODES);
    count_deg<<<dim3((N_EDGES + 255) / 256), dim3(256), 0, stream>>>(dst, deg);
    scan1<<<dim3(NBLK), dim3(SCAN_B), 0, stream>>>(deg, rowptr, bsum);
    scan2<<<dim3(1), dim3(64), 0, stream>>>(bsum, boff, NBLK);
    scan3<<<dim3(NBLK), dim3(SCAN_B), 0, stream>>>(rowptr, boff, pos);
    fill_csr<<<dim3((N_EDGES + 255) / 256), dim3(256), 0, stream>>>(src, dst, pos, csr_src);
    gptr_kernel<<<dim3(1), dim3(256), 0, stream>>>(gid, gptr);

    // ---- weight splits (transposed) ----
    split_wt<<<dim3(D1 / 32, F_IN / 32), dim3(32, 8), 0, stream>>>(W1, Bt1, F_IN, D1);
    split_wt<<<dim3(D2 / 32, D1 / 32),   dim3(32, 8), 0, stream>>>(W2, Bt2, D1, D2);
    split_wt<<<dim3(D3 / 32, D2 / 32),   dim3(32, 8), 0, stream>>>(W3, Bt3, D2, D3);
    split_wt<<<dim3(HIDG / 32, D3 / 32), dim3(32, 8), 0, stream>>>(Wg1, Btg, D3, HIDG);

    // ---- layer-1 input split ----
    split_x<<<dim3((N_NODES * F_IN / 4 + 255) / 256), dim3(256), 0, stream>>>(node_feat, Xsp, N_NODES, F_IN);

    auto zero_eler = [&]() {
        zero_int<<<dim3((2 * N_NODES * NH + 255) / 256), dim3(256), 0, stream>>>((int*)el, 2 * N_NODES * NH);
    };

    // ---- layer 1 (attn fused into GEMM epilogue) ----
    zero_eler();
    gemm_mfma<false, false, 1, 6><<<dim3(157 * 2), dim3(256), 0, stream>>>(
        Xsp, Bt1, nullptr, featb, N_NODES, D1, F_IN, 2, F_IN, al1, ar1, el, er);
    attn_softmax<<<dim3(N_NODES), dim3(64), 0, stream>>>(el, er, rowptr, csr_src, csrE, rden);
    aggregate_x<6, 2, D1><<<dim3(N_NODES * 2), dim3(64), 0, stream>>>(featb, csrE, rden, rowptr, csr_src, b1, Xsp);

    // ---- layer 2 ----
    zero_eler();
    gemm_mfma<false, false, 1, 7><<<dim3(157 * 4), dim3(256), 0, stream>>>(
        Xsp, Bt2, nullptr, featb, N_NODES, D2, D1, 4, D1, al2, ar2, el, er);
    attn_softmax<<<dim3(N_NODES), dim3(64), 0, stream>>>(el, er, rowptr, csr_src, csrE, rden);
    aggregate_x<7, 4, D2><<<dim3(N_NODES * 4), dim3(64), 0, stream>>>(featb, csrE, rden, rowptr, csr_src, b2, Xsp);

    // ---- layer 3 (XCD-pinned col chunks x8) ----
    zero_eler();
    gemm_mfma<false, false, 1, 8><<<dim3(157 * 8), dim3(256), 0, stream>>>(
        Xsp, Bt3, nullptr, featb, N_NODES, D3, D2, 8, D2, al3, ar3, el, er);
    attn_softmax<<<dim3(N_NODES), dim3(64), 0, stream>>>(el, er, rowptr, csr_src, csrE, rden);
    aggregate_x<8, 8, D3><<<dim3(N_NODES * 8), dim3(64), 0, stream>>>(featb, csrE, rden, rowptr, csr_src, b3, Xsp);

    // ---- pooling: K-split x4 gate GEMM -> fused reduce ----
    gemm_mfma<false, false, 2, 0><<<dim3(157, 4), dim3(256), 0, stream>>>(
        Xsp, Btg, nullptr, partial, N_NODES, HIDG, D3, 1, D3 / 4, nullptr, nullptr, nullptr, nullptr);
    gate_reduce<<<dim3(N_NODES), dim3(128), 0, stream>>>(partial, bg1, Wg2, bg2, gate);
    gate_stats<<<dim3(N_GRAPH), dim3(64), 0, stream>>>(gate, gptr, anorm);
    pool_gather<<<dim3(D3 / 128, N_GRAPH), dim3(64), 0, stream>>>(Xsp, anorm, gptr, gemb);
    heads_partial<<<dim3(N_GRAPH, KS_HEADS), dim3(256), 0, stream>>>(gemb, Wmu, Wlv, hpart);
    heads_reduce<<<dim3(N_GRAPH), dim3(256), 0, stream>>>(hpart, bmu, blv, out);
}

// Round 14
// 451.418 us; speedup vs baseline: 1.1390x; 1.1390x over previous
//
#include <hip/hip_runtime.h>
#include <math.h>

// ---- problem constants (fixed by the reference) ----
constexpr int N_NODES = 20000;
constexpr int N_EDGES = 320000;
constexpr int N_GRAPH = 200;
constexpr int F_IN    = 128;
constexpr int NH      = 4;
constexpr int O1 = 64,  O2 = 128, O3 = 256;
constexpr int D1 = 256, D2 = 512, D3 = 1024;
constexpr int LAT  = 128;
constexpr int HIDG = 128;
constexpr int KS_HEADS = 8;
constexpr float NEG_SLOPE = 0.2f;

typedef __attribute__((ext_vector_type(8))) short bf16x8;
typedef __attribute__((ext_vector_type(4))) float f32x4;
typedef __attribute__((ext_vector_type(2))) ushort ushortx2;

// bf16 split: x ~= hi + lo, both RNE-rounded bf16 (stored as raw ushort)
__device__ inline void bsplit(float x, ushort& h, ushort& l) {
    unsigned u = __float_as_uint(x);
    unsigned rh = (u + 0x7fffu + ((u >> 16) & 1u)) & 0xffff0000u;
    h = (ushort)(rh >> 16);
    float res = x - __uint_as_float(rh);
    unsigned u2 = __float_as_uint(res);
    l = (ushort)((u2 + 0x7fffu + ((u2 >> 16) & 1u)) >> 16);
}
__device__ inline ushort f2bf(float x) {
    unsigned u = __float_as_uint(x);
    return (ushort)((u + 0x7fffu + ((u >> 16) & 1u)) >> 16);
}
__device__ inline float bf2f(ushort u) { return __uint_as_float(((unsigned)u) << 16); }

// ================= CSR build =================
__global__ void zero_int(int* __restrict__ p, int n) {
    int i = blockIdx.x * blockDim.x + threadIdx.x;
    if (i < n) p[i] = 0;
}

__global__ void count_deg(const int* __restrict__ dst, int* __restrict__ deg) {
    int e = blockIdx.x * blockDim.x + threadIdx.x;
    if (e < N_EDGES) atomicAdd(&deg[dst[e]], 1);
}

constexpr int SCAN_B = 512;
__global__ __launch_bounds__(SCAN_B)
void scan1(const int* __restrict__ deg, int* __restrict__ rowptr, int* __restrict__ bsum) {
    __shared__ int s[SCAN_B];
    int tid = threadIdx.x;
    int i = blockIdx.x * SCAN_B + tid;
    int v = (i < N_NODES) ? deg[i] : 0;
    s[tid] = v;
    __syncthreads();
    for (int off = 1; off < SCAN_B; off <<= 1) {
        int add = (tid >= off) ? s[tid - off] : 0;
        __syncthreads();
        s[tid] += add;
        __syncthreads();
    }
    if (i < N_NODES) rowptr[i] = s[tid] - v;
    if (tid == SCAN_B - 1) bsum[blockIdx.x] = s[tid];
}

__global__ void scan2(const int* __restrict__ bsum, int* __restrict__ boff, int nblk) {
    if (threadIdx.x == 0 && blockIdx.x == 0) {
        int run = 0;
        for (int b = 0; b < nblk; ++b) { boff[b] = run; run += bsum[b]; }
    }
}

__global__ __launch_bounds__(SCAN_B)
void scan3(int* __restrict__ rowptr, const int* __restrict__ boff, int* __restrict__ pos) {
    int i = blockIdx.x * SCAN_B + threadIdx.x;
    if (i < N_NODES) {
        int v = rowptr[i] + boff[blockIdx.x];
        rowptr[i] = v;
        pos[i] = v;
    }
    if (i == 0) rowptr[N_NODES] = N_EDGES;
}

__global__ void fill_csr(const int* __restrict__ src, const int* __restrict__ dst,
                         int* __restrict__ pos, int* __restrict__ csr_src) {
    int e = blockIdx.x * blockDim.x + threadIdx.x;
    if (e >= N_EDGES) return;
    int slot = atomicAdd(&pos[dst[e]], 1);
    csr_src[slot] = src[e];
}

__global__ void gptr_kernel(const int* __restrict__ gid, int* __restrict__ gptr) {
    int g = blockIdx.x * blockDim.x + threadIdx.x;
    if (g > N_GRAPH) return;
    int lo = 0, hi = N_NODES;
    while (lo < hi) { int mid = (lo + hi) >> 1; if (gid[mid] < g) lo = mid + 1; else hi = mid; }
    gptr[g] = lo;
}

// ================= conversion kernels =================
__global__ void split_x(const float* __restrict__ X, ushort* __restrict__ S, int M, int K) {
    int i = blockIdx.x * 256 + threadIdx.x;
    int total = (M * K) >> 2;
    if (i >= total) return;
    int e0 = i << 2;
    int m = e0 / K, k = e0 % K;
    float4 v = *(const float4*)&X[(size_t)m * K + k];
    ushort h[4], l[4];
    bsplit(v.x, h[0], l[0]); bsplit(v.y, h[1], l[1]);
    bsplit(v.z, h[2], l[2]); bsplit(v.w, h[3], l[3]);
    uint2 hp, lp;
    hp.x = (unsigned)h[0] | ((unsigned)h[1] << 16);
    hp.y = (unsigned)h[2] | ((unsigned)h[3] << 16);
    lp.x = (unsigned)l[0] | ((unsigned)l[1] << 16);
    lp.y = (unsigned)l[2] | ((unsigned)l[3] << 16);
    *(uint2*)&S[(size_t)m * 2 * K + k] = hp;
    *(uint2*)&S[(size_t)m * 2 * K + K + k] = lp;
}

__global__ __launch_bounds__(256)
void split_wt(const float* __restrict__ W, ushort* __restrict__ Bt, int K, int N) {
    __shared__ float t[32][33];
    int n0 = blockIdx.x * 32, k0 = blockIdx.y * 32;
    int tx = threadIdx.x, ty = threadIdx.y;   // 32 x 8
    for (int j = 0; j < 32; j += 8)
        t[ty + j][tx] = W[(size_t)(k0 + ty + j) * N + n0 + tx];
    __syncthreads();
    for (int j = 0; j < 32; j += 8) {
        float v = t[tx][ty + j];
        int n = n0 + ty + j, k = k0 + tx;
        ushort h, l;
        bsplit(v, h, l);
        Bt[(size_t)n * 2 * K + k] = h;
        Bt[(size_t)n * 2 * K + K + k] = l;
    }
}

// ================= bf16x3 merged-segment MFMA GEMM =================
#define GLOAD_LDS16(g, s) \
    __builtin_amdgcn_global_load_lds((const __attribute__((address_space(1))) void*)(g), \
                                     (__attribute__((address_space(3))) void*)(s), 16, 0, 0)

template<bool BIAS, bool RELU, int OMODE>
__global__ __launch_bounds__(256)
void gemm_mfma(const ushort* __restrict__ Asp, const ushort* __restrict__ Bt,
               const float* __restrict__ bias, void* __restrict__ Cout,
               int M, int N, int K, int ntn, int kchunk) {
    __shared__ __align__(16) ushort lds[4 * 128 * 64];   // 64 KB
    constexpr int AH = 0, AL = 128 * 64, BH = 2 * 128 * 64, BL = 3 * 128 * 64;

    const int nwg = gridDim.x;
    int bid = blockIdx.x;
    int q = nwg >> 3, r = nwg & 7;
    int xcd = bid & 7, local = bid >> 3;
    int wg = (xcd < r) ? (xcd * (q + 1) + local) : (r * (q + 1) + (xcd - r) * q + local);
    const int tm = wg / ntn, tn = wg % ntn;

    const int tid = threadIdx.x;
    const int w = tid >> 6, l = tid & 63;
    const int wr = w >> 1, wc = w & 1;
    const size_t sA = 2 * (size_t)K;

    const int ld8 = l >> 3;
    const int stg_col = ((l & 7) ^ ld8) << 3;
    const int r15 = l & 15, kq = l >> 4;
    const int swz = (l & 7) << 4;

    const int k_begin = blockIdx.y * kchunk;
    const int k_end = (k_begin + kchunk < K) ? (k_begin + kchunk) : K;

    f32x4 acc[4][4];
    #pragma unroll
    for (int m = 0; m < 4; ++m)
        #pragma unroll
        for (int n = 0; n < 4; ++n)
            acc[m][n] = 0.f;

    for (int k0 = k_begin; k0 < k_end; k0 += 64) {
        #pragma unroll
        for (int i = 0; i < 4; ++i) {
            int r0 = w * 32 + i * 8;
            int garow = tm * 128 + r0 + ld8;
            if (garow > M - 1) garow = M - 1;
            const ushort* gaH = Asp + (size_t)garow * sA + k0 + stg_col;
            GLOAD_LDS16(gaH, &lds[AH + r0 * 64]);
            GLOAD_LDS16(gaH + K, &lds[AL + r0 * 64]);
            int gbrow = tn * 128 + r0 + ld8;
            const ushort* gbH = Bt + (size_t)gbrow * sA + k0 + stg_col;
            GLOAD_LDS16(gbH, &lds[BH + r0 * 64]);
            GLOAD_LDS16(gbH + K, &lds[BL + r0 * 64]);
        }
        asm volatile("s_waitcnt vmcnt(0)");
        __syncthreads();

        #pragma unroll
        for (int ks = 0; ks < 2; ++ks) {
            const int kbyte = (ks * 64 + kq * 16) ^ swz;
            bf16x8 ah[4], bh[4], xl[4];
            #pragma unroll
            for (int m = 0; m < 4; ++m) {
                int row = wr * 64 + m * 16 + r15;
                ah[m] = *(const bf16x8*)((const char*)&lds[AH] + row * 128 + kbyte);
            }
            #pragma unroll
            for (int n = 0; n < 4; ++n) {
                int row = wc * 64 + n * 16 + r15;
                bh[n] = *(const bf16x8*)((const char*)&lds[BH] + row * 128 + kbyte);
            }
            #pragma unroll
            for (int m = 0; m < 4; ++m)
                #pragma unroll
                for (int n = 0; n < 4; ++n)
                    acc[m][n] = __builtin_amdgcn_mfma_f32_16x16x32_bf16(ah[m], bh[n], acc[m][n], 0, 0, 0);
            #pragma unroll
            for (int m = 0; m < 4; ++m) {
                int row = wr * 64 + m * 16 + r15;
                xl[m] = *(const bf16x8*)((const char*)&lds[AL] + row * 128 + kbyte);
            }
            #pragma unroll
            for (int m = 0; m < 4; ++m)
                #pragma unroll
                for (int n = 0; n < 4; ++n)
                    acc[m][n] = __builtin_amdgcn_mfma_f32_16x16x32_bf16(xl[m], bh[n], acc[m][n], 0, 0, 0);
            #pragma unroll
            for (int n = 0; n < 4; ++n) {
                int row = wc * 64 + n * 16 + r15;
                xl[n] = *(const bf16x8*)((const char*)&lds[BL] + row * 128 + kbyte);
            }
            #pragma unroll
            for (int m = 0; m < 4; ++m)
                #pragma unroll
                for (int n = 0; n < 4; ++n)
                    acc[m][n] = __builtin_amdgcn_mfma_f32_16x16x32_bf16(ah[m], xl[n], acc[m][n], 0, 0, 0);
        }
        __syncthreads();
    }

    // ---- epilogue ----
    #pragma unroll
    for (int m = 0; m < 4; ++m) {
        #pragma unroll
        for (int n = 0; n < 4; ++n) {
            #pragma unroll
            for (int j = 0; j < 4; ++j) {
                int row = tm * 128 + wr * 64 + m * 16 + kq * 4 + j;
                int col = tn * 128 + wc * 64 + n * 16 + r15;
                if (row < M) {
                    float v = acc[m][n][j];
                    if (BIAS) v += bias[col];
                    if (RELU) v = fmaxf(v, 0.f);
                    if (OMODE == 1)
                        ((ushort*)Cout)[(size_t)row * N + col] = f2bf(v);
                    else if (OMODE == 2)
                        ((float*)Cout)[(size_t)blockIdx.y * M * N + (size_t)row * N + col] = v;
                    else
                        ((float*)Cout)[(size_t)row * N + col] = v;
                }
            }
        }
    }
}

// ================= per-node attention halves (bf16 plane, ushortx2/lane) ====
__global__ __launch_bounds__(256)
void attn_lr_b(const ushort* __restrict__ feat, const float* __restrict__ al,
               const float* __restrict__ ar, float* __restrict__ el,
               float* __restrict__ er, int O) {
    int n = blockIdx.x;
    int h = threadIdx.x >> 6;
    int lane = threadIdx.x & 63;
    const ushort* fr = feat + (size_t)n * (NH * O) + h * O;
    const float* alr = al + h * O;
    const float* arr = ar + h * O;
    float sl = 0.f, sr = 0.f;
    for (int o = lane * 2; o < O; o += 128) {
        ushortx2 u = *(const ushortx2*)(fr + o);
        float f0 = bf2f(u[0]), f1 = bf2f(u[1]);
        float2 a2 = *(const float2*)(alr + o);
        float2 r2 = *(const float2*)(arr + o);
        sl += f0 * a2.x + f1 * a2.y;
        sr += f0 * r2.x + f1 * r2.y;
    }
    #pragma unroll
    for (int off = 32; off; off >>= 1) {
        sl += __shfl_down(sl, off);
        sr += __shfl_down(sr, off);
    }
    if (lane == 0) {
        el[n * NH + h] = sl;
        er[n * NH + h] = sr;
    }
}

// ================= per-dst edge softmax over CSR (head-major csr_e) =========
// First per-lane edge is register-cached: its raw-e skips the csrE round trip.
__global__ __launch_bounds__(64)
void attn_softmax(const float* __restrict__ el, const float* __restrict__ er,
                  const int* __restrict__ rowptr, const int* __restrict__ csr_src,
                  float* __restrict__ csrE, float* __restrict__ rden) {
    int d = blockIdx.x;
    int lane = threadIdx.x;
    int base = __builtin_amdgcn_readfirstlane(rowptr[d]);
    int end  = __builtin_amdgcn_readfirstlane(rowptr[d + 1]);
    float4 erd = *(const float4*)(er + d * NH);
    const int s0 = base + lane;
    const bool have0 = s0 < end;

    float c0 = 0.f, c1 = 0.f, c2 = 0.f, c3 = 0.f;   // reg-cached raw e for s0
    float mx[NH] = {-INFINITY, -INFINITY, -INFINITY, -INFINITY};

    if (have0) {
        int sn = csr_src[s0];
        float4 elv = *(const float4*)(el + sn * NH);
        c0 = elv.x + erd.x; c1 = elv.y + erd.y;
        c2 = elv.z + erd.z; c3 = elv.w + erd.w;
        c0 = (c0 >= 0.f) ? c0 : NEG_SLOPE * c0;
        c1 = (c1 >= 0.f) ? c1 : NEG_SLOPE * c1;
        c2 = (c2 >= 0.f) ? c2 : NEG_SLOPE * c2;
        c3 = (c3 >= 0.f) ? c3 : NEG_SLOPE * c3;
        mx[0] = c0; mx[1] = c1; mx[2] = c2; mx[3] = c3;
    }
    for (int s = s0 + 64; s < end; s += 64) {
        int sn = csr_src[s];
        float4 elv = *(const float4*)(el + sn * NH);
        float e0 = elv.x + erd.x, e1 = elv.y + erd.y;
        float e2 = elv.z + erd.z, e3 = elv.w + erd.w;
        e0 = (e0 >= 0.f) ? e0 : NEG_SLOPE * e0;
        e1 = (e1 >= 0.f) ? e1 : NEG_SLOPE * e1;
        e2 = (e2 >= 0.f) ? e2 : NEG_SLOPE * e2;
        e3 = (e3 >= 0.f) ? e3 : NEG_SLOPE * e3;
        csrE[(size_t)0 * N_EDGES + s] = e0;
        csrE[(size_t)1 * N_EDGES + s] = e1;
        csrE[(size_t)2 * N_EDGES + s] = e2;
        csrE[(size_t)3 * N_EDGES + s] = e3;
        mx[0] = fmaxf(mx[0], e0); mx[1] = fmaxf(mx[1], e1);
        mx[2] = fmaxf(mx[2], e2); mx[3] = fmaxf(mx[3], e3);
    }
    #pragma unroll
    for (int h = 0; h < NH; ++h)
        #pragma unroll
        for (int off = 32; off; off >>= 1)
            mx[h] = fmaxf(mx[h], __shfl_xor(mx[h], off));

    float sm[NH] = {0.f, 0.f, 0.f, 0.f};
    if (have0) {
        float x0 = expf(c0 - mx[0]), x1 = expf(c1 - mx[1]);
        float x2 = expf(c2 - mx[2]), x3 = expf(c3 - mx[3]);
        csrE[(size_t)0 * N_EDGES + s0] = x0;
        csrE[(size_t)1 * N_EDGES + s0] = x1;
        csrE[(size_t)2 * N_EDGES + s0] = x2;
        csrE[(size_t)3 * N_EDGES + s0] = x3;
        sm[0] += x0; sm[1] += x1; sm[2] += x2; sm[3] += x3;
    }
    for (int s = s0 + 64; s < end; s += 64) {
        #pragma unroll
        for (int h = 0; h < NH; ++h) {
            float ex = expf(csrE[(size_t)h * N_EDGES + s] - mx[h]);
            csrE[(size_t)h * N_EDGES + s] = ex;
            sm[h] += ex;
        }
    }
    #pragma unroll
    for (int h = 0; h < NH; ++h)
        #pragma unroll
        for (int off = 32; off; off >>= 1)
            sm[h] += __shfl_xor(sm[h], off);

    if (lane == 0) {
        #pragma unroll
        for (int h = 0; h < NH; ++h)
            rden[d * NH + h] = 1.f / fmaxf(sm[h], 1e-9f);
    }
}

// ================= XCD-pinned gather aggregation (bf16 feat plane) ==========
template<int OSHIFT, int NCH, int D>
__global__ __launch_bounds__(64)
void aggregate_x(const ushort* __restrict__ feat, const float* __restrict__ csrE,
                 const float* __restrict__ rden, const int* __restrict__ rowptr,
                 const int* __restrict__ csr_src, const float* __restrict__ bias,
                 ushort* __restrict__ Ssp) {
    int bid = blockIdx.x;
    int chunk = bid % NCH;
    int d = bid / NCH;
    int t = threadIdx.x;
    int base = __builtin_amdgcn_readfirstlane(rowptr[d]);
    int end  = __builtin_amdgcn_readfirstlane(rowptr[d + 1]);
    const int col0 = chunk * 128 + t * 2;
    const int h = col0 >> OSHIFT;
    const float* eh = csrE + (size_t)h * N_EDGES;
    const ushort* fcol = feat + col0;

    float acc0 = 0.f, acc1 = 0.f;

    int s = base;
    for (; s < end && (s & 3); ++s) {
        int sn = csr_src[s];
        float a = eh[s];
        ushortx2 u = *(const ushortx2*)(fcol + (size_t)sn * D);
        acc0 += bf2f(u[0]) * a; acc1 += bf2f(u[1]) * a;
    }
    for (; s + 7 < end; s += 8) {
        int4 sa = *(const int4*)(csr_src + s);
        int4 sb = *(const int4*)(csr_src + s + 4);
        float4 aa = *(const float4*)(eh + s);
        float4 ab = *(const float4*)(eh + s + 4);
        ushortx2 u0 = *(const ushortx2*)(fcol + (size_t)sa.x * D);
        ushortx2 u1 = *(const ushortx2*)(fcol + (size_t)sa.y * D);
        ushortx2 u2 = *(const ushortx2*)(fcol + (size_t)sa.z * D);
        ushortx2 u3 = *(const ushortx2*)(fcol + (size_t)sa.w * D);
        ushortx2 u4 = *(const ushortx2*)(fcol + (size_t)sb.x * D);
        ushortx2 u5 = *(const ushortx2*)(fcol + (size_t)sb.y * D);
        ushortx2 u6 = *(const ushortx2*)(fcol + (size_t)sb.z * D);
        ushortx2 u7 = *(const ushortx2*)(fcol + (size_t)sb.w * D);
        acc0 += bf2f(u0[0]) * aa.x; acc1 += bf2f(u0[1]) * aa.x;
        acc0 += bf2f(u1[0]) * aa.y; acc1 += bf2f(u1[1]) * aa.y;
        acc0 += bf2f(u2[0]) * aa.z; acc1 += bf2f(u2[1]) * aa.z;
        acc0 += bf2f(u3[0]) * aa.w; acc1 += bf2f(u3[1]) * aa.w;
        acc0 += bf2f(u4[0]) * ab.x; acc1 += bf2f(u4[1]) * ab.x;
        acc0 += bf2f(u5[0]) * ab.y; acc1 += bf2f(u5[1]) * ab.y;
        acc0 += bf2f(u6[0]) * ab.z; acc1 += bf2f(u6[1]) * ab.z;
        acc0 += bf2f(u7[0]) * ab.w; acc1 += bf2f(u7[1]) * ab.w;
    }
    if (s + 3 < end) {
        int4 sn = *(const int4*)(csr_src + s);
        float4 av = *(const float4*)(eh + s);
        ushortx2 u0 = *(const ushortx2*)(fcol + (size_t)sn.x * D);
        ushortx2 u1 = *(const ushortx2*)(fcol + (size_t)sn.y * D);
        ushortx2 u2 = *(const ushortx2*)(fcol + (size_t)sn.z * D);
        ushortx2 u3 = *(const ushortx2*)(fcol + (size_t)sn.w * D);
        acc0 += bf2f(u0[0]) * av.x; acc1 += bf2f(u0[1]) * av.x;
        acc0 += bf2f(u1[0]) * av.y; acc1 += bf2f(u1[1]) * av.y;
        acc0 += bf2f(u2[0]) * av.z; acc1 += bf2f(u2[1]) * av.z;
        acc0 += bf2f(u3[0]) * av.w; acc1 += bf2f(u3[1]) * av.w;
        s += 4;
    }
    for (; s < end; ++s) {
        int sn = csr_src[s];
        float a = eh[s];
        ushortx2 u = *(const ushortx2*)(fcol + (size_t)sn * D);
        acc0 += bf2f(u[0]) * a; acc1 += bf2f(u[1]) * a;
    }

    float rd = rden[d * NH + h];
    float v0 = acc0 * rd + bias[col0];
    float v1 = acc1 * rd + bias[col0 + 1];
    v0 = (v0 > 0.f) ? v0 : expm1f(v0);
    v1 = (v1 > 0.f) ? v1 : expm1f(v1);
    ushort h0, l0, h1, l1;
    bsplit(v0, h0, l0);
    bsplit(v1, h1, l1);
    ushort* hrow = Ssp + (size_t)d * 2 * D;
    ushortx2 hp, lp;
    hp[0] = h0; hp[1] = h1;
    lp[0] = l0; lp[1] = l1;
    *(ushortx2*)(hrow + col0) = hp;
    *(ushortx2*)(hrow + D + col0) = lp;
}

// ================= gate reduce: partials -> gate scalar =================
__global__ __launch_bounds__(128)
void gate_reduce(const float* __restrict__ part, const float* __restrict__ bg1,
                 const float* __restrict__ Wg2, const float* __restrict__ bg2,
                 float* __restrict__ gate) {
    int n = blockIdx.x;
    int t = threadIdx.x;
    constexpr size_t CH = (size_t)N_NODES * HIDG;
    size_t idx = (size_t)n * HIDG + t;
    float v = part[idx] + part[CH + idx] + part[2 * CH + idx] + part[3 * CH + idx] + bg1[t];
    v = fmaxf(v, 0.f) * Wg2[t];
    __shared__ float red[128];
    red[t] = v;
    __syncthreads();
    for (int s = 64; s; s >>= 1) {
        if (t < s) red[t] += red[t + s];
        __syncthreads();
    }
    if (t == 0) gate[n] = red[0] + bg2[0];
}

__global__ __launch_bounds__(64)
void gate_stats(const float* __restrict__ gate, const int* __restrict__ gptr,
                float* __restrict__ anorm) {
    int g = blockIdx.x;
    int lane = threadIdx.x;
    int s = __builtin_amdgcn_readfirstlane(gptr[g]);
    int e = __builtin_amdgcn_readfirstlane(gptr[g + 1]);
    float m = -INFINITY;
    for (int n = s + lane; n < e; n += 64) m = fmaxf(m, gate[n]);
    #pragma unroll
    for (int off = 32; off; off >>= 1) m = fmaxf(m, __shfl_xor(m, off));
    float sum = 0.f;
    for (int n = s + lane; n < e; n += 64) sum += expf(gate[n] - m);
    #pragma unroll
    for (int off = 32; off; off >>= 1) sum += __shfl_xor(sum, off);
    float inv = 1.f / fmaxf(sum, 1e-9f);
    for (int n = s + lane; n < e; n += 64) anorm[n] = expf(gate[n] - m) * inv;
}

// gemb[g] = sum_n anorm[n]*h3[n]; grid (D3/128, G), 64 threads, 2 cols/thread
__global__ __launch_bounds__(64)
void pool_gather(const ushort* __restrict__ h3sp, const float* __restrict__ anorm,
                 const int* __restrict__ gptr, float* __restrict__ gemb) {
    int g = blockIdx.y;
    int col = blockIdx.x * 128 + threadIdx.x * 2;
    float acc0 = 0.f, acc1 = 0.f;
    int s = __builtin_amdgcn_readfirstlane(gptr[g]);
    int e = __builtin_amdgcn_readfirstlane(gptr[g + 1]);
    int n = s;
    for (; n + 3 < e; n += 4) {
        const ushort* r0 = h3sp + (size_t)(n + 0) * 2 * D3;
        const ushort* r1 = h3sp + (size_t)(n + 1) * 2 * D3;
        const ushort* r2 = h3sp + (size_t)(n + 2) * 2 * D3;
        const ushort* r3 = h3sp + (size_t)(n + 3) * 2 * D3;
        float a0 = anorm[n], a1 = anorm[n + 1], a2 = anorm[n + 2], a3 = anorm[n + 3];
        ushortx2 h0 = *(const ushortx2*)(r0 + col), l0 = *(const ushortx2*)(r0 + D3 + col);
        ushortx2 h1 = *(const ushortx2*)(r1 + col), l1 = *(const ushortx2*)(r1 + D3 + col);
        ushortx2 h2 = *(const ushortx2*)(r2 + col), l2 = *(const ushortx2*)(r2 + D3 + col);
        ushortx2 h3 = *(const ushortx2*)(r3 + col), l3 = *(const ushortx2*)(r3 + D3 + col);
        acc0 += a0 * (bf2f(h0[0]) + bf2f(l0[0])); acc1 += a0 * (bf2f(h0[1]) + bf2f(l0[1]));
        acc0 += a1 * (bf2f(h1[0]) + bf2f(l1[0])); acc1 += a1 * (bf2f(h1[1]) + bf2f(l1[1]));
        acc0 += a2 * (bf2f(h2[0]) + bf2f(l2[0])); acc1 += a2 * (bf2f(h2[1]) + bf2f(l2[1]));
        acc0 += a3 * (bf2f(h3[0]) + bf2f(l3[0])); acc1 += a3 * (bf2f(h3[1]) + bf2f(l3[1]));
    }
    for (; n < e; ++n) {
        const ushort* r0 = h3sp + (size_t)n * 2 * D3;
        float a0 = anorm[n];
        ushortx2 h0 = *(const ushortx2*)(r0 + col), l0 = *(const ushortx2*)(r0 + D3 + col);
        acc0 += a0 * (bf2f(h0[0]) + bf2f(l0[0]));
        acc1 += a0 * (bf2f(h0[1]) + bf2f(l0[1]));
    }
    gemb[(size_t)g * D3 + col] = acc0;
    gemb[(size_t)g * D3 + col + 1] = acc1;
}

// ================= heads: k-split partial + reduce =================
__global__ __launch_bounds__(256)
void heads_partial(const float* __restrict__ gemb, const float* __restrict__ Wmu,
                   const float* __restrict__ Wlv, float* __restrict__ part) {
    int g = blockIdx.x, kc = blockIdx.y;
    int t = threadIdx.x;
    int j = t & 127;
    bool lv = t >= 128;
    __shared__ float e[128];
    if (t < 128) e[t] = gemb[(size_t)g * D3 + kc * 128 + t];
    __syncthreads();
    const float* W = (lv ? Wlv : Wmu) + (size_t)(kc * 128) * LAT + j;
    float s = 0.f;
    #pragma unroll 8
    for (int k = 0; k < 128; ++k) s += e[k] * W[(size_t)k * LAT];
    part[((size_t)kc * N_GRAPH + g) * 256 + t] = s;
}

__global__ __launch_bounds__(256)
void heads_reduce(const float* __restrict__ part, const float* __restrict__ bmu,
                  const float* __restrict__ blv, float* __restrict__ out) {
    int g = blockIdx.x;
    int t = threadIdx.x;
    int j = t & 127;
    bool lv = t >= 128;
    float s = 0.f;
    #pragma unroll
    for (int kc = 0; kc < KS_HEADS; ++kc)
        s += part[((size_t)kc * N_GRAPH + g) * 256 + t];
    s += (lv ? blv : bmu)[j];
    out[(lv ? (size_t)N_GRAPH * LAT : 0) + (size_t)g * LAT + j] = s;
}

// ================= host launch =================
extern "C" void kernel_launch(void* const* d_in, const int* in_sizes, int n_in,
                              void* d_out, int out_size, void* d_ws, size_t ws_size,
                              hipStream_t stream) {
    const float* node_feat = (const float*)d_in[0];
    const int*   src = (const int*)d_in[1];
    const int*   dst = (const int*)d_in[2];
    const int*   gid = (const int*)d_in[3];
    const float* W1  = (const float*)d_in[4];
    const float* al1 = (const float*)d_in[5];
    const float* ar1 = (const float*)d_in[6];
    const float* b1  = (const float*)d_in[7];
    const float* W2  = (const float*)d_in[8];
    const float* al2 = (const float*)d_in[9];
    const float* ar2 = (const float*)d_in[10];
    const float* b2  = (const float*)d_in[11];
    const float* W3  = (const float*)d_in[12];
    const float* al3 = (const float*)d_in[13];
    const float* ar3 = (const float*)d_in[14];
    const float* b3  = (const float*)d_in[15];
    const float* Wg1 = (const float*)d_in[16];
    const float* bg1 = (const float*)d_in[17];
    const float* Wg2 = (const float*)d_in[18];
    const float* bg2 = (const float*)d_in[19];
    const float* Wmu = (const float*)d_in[20];
    const float* bmu = (const float*)d_in[21];
    const float* Wlv = (const float*)d_in[22];
    const float* blv = (const float*)d_in[23];
    float* out = (float*)d_out;

    // ---- workspace carve ----
    char* wsb = (char*)d_ws;
    float* bufA   = (float*)wsb;                                   // N*D3 f32 region
    wsb += (size_t)N_NODES * D3 * 4;
    ushort* Xsp   = (ushort*)wsb;                                  // N*2048 bf16 (split acts)
    wsb += (size_t)N_NODES * 2048 * 2;
    ushort* Bt1   = (ushort*)wsb; wsb += (size_t)D1 * 2 * F_IN * 2;
    ushort* Bt2   = (ushort*)wsb; wsb += (size_t)D2 * 2 * D1 * 2;
    ushort* Bt3   = (ushort*)wsb; wsb += (size_t)D3 * 2 * D2 * 2;
    ushort* Btg   = (ushort*)wsb; wsb += (size_t)HIDG * 2 * D3 * 2;
    float* el     = (float*)wsb;  wsb += (size_t)N_NODES * NH * 4;
    float* er     = (float*)wsb;  wsb += (size_t)N_NODES * NH * 4;
    float* rden   = (float*)wsb;  wsb += (size_t)N_NODES * NH * 4;
    float* csrE   = (float*)wsb;  wsb += (size_t)N_EDGES * NH * 4;  // head-major [NH][E]
    float* gate   = (float*)wsb;  wsb += (size_t)N_NODES * 4;
    float* anorm  = (float*)wsb;  wsb += (size_t)N_NODES * 4;
    int* deg      = (int*)wsb;    wsb += (size_t)N_NODES * 4;
    int* rowptr   = (int*)wsb;    wsb += (size_t)(N_NODES + 1) * 4;
    int* pos      = (int*)wsb;    wsb += (size_t)N_NODES * 4;
    int* csr_src  = (int*)wsb;    wsb += (size_t)N_EDGES * 4;
    int* bsum     = (int*)wsb;    wsb += 64 * 4;
    int* boff     = (int*)wsb;    wsb += 64 * 4;
    int* gptr     = (int*)wsb;    wsb += (size_t)(N_GRAPH + 1) * 4;
    ushort* featb = (ushort*)bufA;                                 // bf16 feat plane alias
    float* partial = bufA;                                         // pool K-split partials (4*N*128)
    float* gemb   = bufA + (size_t)4 * N_NODES * HIDG;             // G*D3
    float* hpart  = gemb + (size_t)N_GRAPH * D3;                   // KS*G*256

    // ---- CSR build ----
    constexpr int NBLK = (N_NODES + SCAN_B - 1) / SCAN_B;
    zero_int<<<dim3((N_NODES + 255) / 256), dim3(256), 0, stream>>>(deg, N_NODES);
    count_deg<<<dim3((N_EDGES + 255) / 256), dim3(256), 0, stream>>>(dst, deg);
    scan1<<<dim3(NBLK), dim3(SCAN_B), 0, stream>>>(deg, rowptr, bsum);
    scan2<<<dim3(1), dim3(64), 0, stream>>>(bsum, boff, NBLK);
    scan3<<<dim3(NBLK), dim3(SCAN_B), 0, stream>>>(rowptr, boff, pos);
    fill_csr<<<dim3((N_EDGES + 255) / 256), dim3(256), 0, stream>>>(src, dst, pos, csr_src);
    gptr_kernel<<<dim3(1), dim3(256), 0, stream>>>(gid, gptr);

    // ---- weight splits (transposed) ----
    split_wt<<<dim3(D1 / 32, F_IN / 32), dim3(32, 8), 0, stream>>>(W1, Bt1, F_IN, D1);
    split_wt<<<dim3(D2 / 32, D1 / 32),   dim3(32, 8), 0, stream>>>(W2, Bt2, D1, D2);
    split_wt<<<dim3(D3 / 32, D2 / 32),   dim3(32, 8), 0, stream>>>(W3, Bt3, D2, D3);
    split_wt<<<dim3(HIDG / 32, D3 / 32), dim3(32, 8), 0, stream>>>(Wg1, Btg, D3, HIDG);

    // ---- layer-1 input split ----
    split_x<<<dim3((N_NODES * F_IN / 4 + 255) / 256), dim3(256), 0, stream>>>(node_feat, Xsp, N_NODES, F_IN);

    // ---- layer 1 ----
    gemm_mfma<false, false, 1><<<dim3(157 * 2), dim3(256), 0, stream>>>(Xsp, Bt1, nullptr, featb, N_NODES, D1, F_IN, 2, F_IN);
    attn_lr_b<<<dim3(N_NODES), dim3(256), 0, stream>>>(featb, al1, ar1, el, er, O1);
    attn_softmax<<<dim3(N_NODES), dim3(64), 0, stream>>>(el, er, rowptr, csr_src, csrE, rden);
    aggregate_x<6, 2, D1><<<dim3(N_NODES * 2), dim3(64), 0, stream>>>(featb, csrE, rden, rowptr, csr_src, b1, Xsp);

    // ---- layer 2 ----
    gemm_mfma<false, false, 1><<<dim3(157 * 4), dim3(256), 0, stream>>>(Xsp, Bt2, nullptr, featb, N_NODES, D2, D1, 4, D1);
    attn_lr_b<<<dim3(N_NODES), dim3(256), 0, stream>>>(featb, al2, ar2, el, er, O2);
    attn_softmax<<<dim3(N_NODES), dim3(64), 0, stream>>>(el, er, rowptr, csr_src, csrE, rden);
    aggregate_x<7, 4, D2><<<dim3(N_NODES * 4), dim3(64), 0, stream>>>(featb, csrE, rden, rowptr, csr_src, b2, Xsp);

    // ---- layer 3 (XCD-pinned col chunks x8) ----
    gemm_mfma<false, false, 1><<<dim3(157 * 8), dim3(256), 0, stream>>>(Xsp, Bt3, nullptr, featb, N_NODES, D3, D2, 8, D2);
    attn_lr_b<<<dim3(N_NODES), dim3(256), 0, stream>>>(featb, al3, ar3, el, er, O3);
    attn_softmax<<<dim3(N_NODES), dim3(64), 0, stream>>>(el, er, rowptr, csr_src, csrE, rden);
    aggregate_x<8, 8, D3><<<dim3(N_NODES * 8), dim3(64), 0, stream>>>(featb, csrE, rden, rowptr, csr_src, b3, Xsp);

    // ---- pooling: K-split x4 gate GEMM -> fused reduce ----
    gemm_mfma<false, false, 2><<<dim3(157, 4), dim3(256), 0, stream>>>(Xsp, Btg, nullptr, partial, N_NODES, HIDG, D3, 1, D3 / 4);
    gate_reduce<<<dim3(N_NODES), dim3(128), 0, stream>>>(partial, bg1, Wg2, bg2, gate);
    gate_stats<<<dim3(N_GRAPH), dim3(64), 0, stream>>>(gate, gptr, anorm);
    pool_gather<<<dim3(D3 / 128, N_GRAPH), dim3(64), 0, stream>>>(Xsp, anorm, gptr, gemb);
    heads_partial<<<dim3(N_GRAPH, KS_HEADS), dim3(256), 0, stream>>>(gemb, Wmu, Wlv, hpart);
    heads_reduce<<<dim3(N_GRAPH), dim3(256), 0, stream>>>(hpart, bmu, blv, out);
}